// Round 5
// baseline (687.609 us; speedup 1.0000x reference)
//
#include <hip/hip_runtime.h>

#define NB 64
#define NT 4096
#define CH 16
#define KC (NT/CH)        // 256 chunks per batch
#define GPB 16            // chains (16-lane groups) per 256-thread block
#define ROWB 72           // floats per 4-row block: 64 data + 8 pad (8 mod 32 banks)
#define MATS (4*ROWB)     // 288 floats per matrix buffer
#define LGS (2*MATS + 8)  // 584 floats per group; 584 % 32 == 8 -> group bank shift
#define BX 0
#define BY MATS
#define NA 128            // spectral-norm table size over [0, pi)
#define PI_F 3.14159265358979f

// Wave-synchronous LDS fence (16-lane groups are sub-wave -> lockstep).
#define WSYNC() asm volatile("s_waitcnt lgkmcnt(0)" ::: "memory")

#define MM_FMA(A_, B0_, B1_, B2_, B3_, base) \
  acc[base+0] = fmaf(A_.w, B3_.x, fmaf(A_.z, B2_.x, fmaf(A_.y, B1_.x, fmaf(A_.x, B0_.x, acc[base+0])))); \
  acc[base+1] = fmaf(A_.w, B3_.y, fmaf(A_.z, B2_.y, fmaf(A_.y, B1_.y, fmaf(A_.x, B0_.y, acc[base+1])))); \
  acc[base+2] = fmaf(A_.w, B3_.z, fmaf(A_.z, B2_.z, fmaf(A_.y, B1_.z, fmaf(A_.x, B0_.z, acc[base+2])))); \
  acc[base+3] = fmaf(A_.w, B3_.w, fmaf(A_.z, B2_.w, fmaf(A_.y, B1_.w, fmaf(A_.x, B0_.w, acc[base+3]))));

// Layout: element (row,col): q=row>>2, rr=row&3, gc=col>>2 stored at
// q*ROWB + rr*16 + ((gc^q)<<2) + (col&3).
template<bool CLR>
__device__ __forceinline__ void mmg(float acc[16], const float* sb, int offA, int offB,
                                    const int xA[4], const int xB[4], int trR) {
  if (CLR) {
#pragma unroll
    for (int e = 0; e < 16; ++e) acc[e] = 0.f;
  }
#pragma unroll
  for (int kk = 0; kk < 4; ++kk) {
    const float* pa = sb + offA + trR + xA[kk];
    const float* pb = sb + offB + kk*ROWB + xB[kk];
    float4 a0 = *(const float4*)(pa +  0);
    float4 a1 = *(const float4*)(pa + 16);
    float4 a2 = *(const float4*)(pa + 32);
    float4 a3 = *(const float4*)(pa + 48);
    float4 b0 = *(const float4*)(pb +  0);
    float4 b1 = *(const float4*)(pb + 16);
    float4 b2 = *(const float4*)(pb + 32);
    float4 b3 = *(const float4*)(pb + 48);
    MM_FMA(a0, b0, b1, b2, b3, 0)
    MM_FMA(a1, b0, b1, b2, b3, 4)
    MM_FMA(a2, b0, b1, b2, b3, 8)
    MM_FMA(a3, b0, b1, b2, b3, 12)
  }
}

__device__ __forceinline__ void st4(float* sb, int offD, const float v[16], int trR, int xD) {
  float* p = sb + offD + trR + xD;
#pragma unroll
  for (int rr = 0; rr < 4; ++rr)
    *(float4*)(p + rr*16) = make_float4(v[rr*4+0], v[rr*4+1], v[rr*4+2], v[rr*4+3]);
}

// k0: spectral-norm table rho(theta)=||cos*S1+sin*S2||_2 via power iteration.
__global__ __launch_bounds__(128) void k0_spec(const float* __restrict__ A1,
                                               const float* __restrict__ A2,
                                               float* __restrict__ ws) {
  __shared__ float S1[256], S2[256];
  const int tid = threadIdx.x;
  for (int e = tid; e < 256; e += 128) {
    int i_ = e >> 4, j_ = e & 15;
    S1[e] = A1[i_*16+j_] - A1[j_*16+i_];
    S2[e] = A2[i_*16+j_] - A2[j_*16+i_];
  }
  __syncthreads();
  const float th = (float)tid * (PI_F / NA);
  const float c = cosf(th), s = sinf(th);
  float v[16];
  float n2 = 0.f;
#pragma unroll
  for (int j = 0; j < 16; ++j) { v[j] = sinf(1.7f*(float)(j+1) + th) + 0.25f; n2 += v[j]*v[j]; }
  float inv = rsqrtf(n2);
#pragma unroll
  for (int j = 0; j < 16; ++j) v[j] *= inv;
  float lam = 0.f;
  for (int it = 0; it < 14; ++it) {
    float w[16];
#pragma unroll
    for (int i = 0; i < 16; ++i) {
      float a1 = 0.f, a2 = 0.f;
#pragma unroll
      for (int j = 0; j < 16; ++j) { a1 = fmaf(S1[i*16+j], v[j], a1); a2 = fmaf(S2[i*16+j], v[j], a2); }
      w[i] = c*a1 + s*a2;
    }
    n2 = 0.f;
#pragma unroll
    for (int i = 0; i < 16; ++i) n2 += w[i]*w[i];
    lam = sqrtf(n2);
    inv = (lam > 1e-20f) ? 1.f/lam : 0.f;
#pragma unroll
    for (int i = 0; i < 16; ++i) v[i] = w[i]*inv;
  }
  ws[tid] = lam * 1.05f;
}

// k1: per-chunk local scan; streaming p/u accumulation; 128-VGPR pinned,
// wave-uniform scaling exponent s (squaring loop is a uniform branch).
__global__ __launch_bounds__(256, 4) void k1_chunk(const float* __restrict__ Z,
                                                   const float* __restrict__ A1,
                                                   const float* __restrict__ A2,
                                                   const float* __restrict__ ws,
                                                   float* __restrict__ Aout)
{
  __shared__ __align__(16) float lds[GPB * LGS];
  __shared__ float rhos[NA];
  const int tid = threadIdx.x;
  const int g   = tid >> 4;
  const int u   = tid & 15;
  const int tr  = u >> 2;
  const int tc  = u & 3;
  const int gw  = (tid & 63) >> 4;
  const int trR = tr * ROWB;

  if (tid < NA) rhos[tid] = ws[tid];
  __syncthreads();

  float* sb = lds + g * LGS;
  const int xA[4] = { ((0^tr)<<2), ((1^tr)<<2), ((2^tr)<<2), ((3^tr)<<2) };
  const int xB[4] = { ((tc^0)<<2), ((tc^1)<<2), ((tc^2)<<2), ((tc^3)<<2) };
  const int xD    = ((tc^tr)<<2);

  const int cid    = blockIdx.x * GPB + g;
  const int b      = cid >> 8;          // / KC  (KC = 256)
  const int kchunk = cid & (KC-1);
  const int t0     = kchunk * CH;

  const float trtc = (tr == tc) ? 1.f : 0.f;
  float s1t[16], s2t[16];
#pragma unroll
  for (int rr = 0; rr < 4; ++rr)
#pragma unroll
    for (int cc = 0; cc < 4; ++cc) {
      int r_ = 4*tr + rr, c_ = 4*tc + cc;
      s1t[rr*4+cc] = A1[r_*16 + c_] - A1[c_*16 + r_];
      s2t[rr*4+cc] = A2[r_*16 + c_] - A2[c_*16 + r_];
    }

  float2 za = *(const float2*)&Z[(size_t)(b*NT + t0 + u) * 2];

  float lt[16], acc[16], gt[16], pp[16], uu[16];
#pragma unroll
  for (int rr = 0; rr < 4; ++rr)
#pragma unroll
    for (int cc = 0; cc < 4; ++cc) lt[rr*4+cc] = (rr == cc) ? trtc : 0.f;

  const float C3 = 1.f/6.f,   C4 = 1.f/24.f,   C5 = 1.f/120.f,
              C6 = 1.f/720.f, C7 = 1.f/5040.f, C8 = 1.f/40320.f;

  for (int tt = 0; tt < CH; ++tt) {
    const int t = t0 + tt;
    const size_t obase = (size_t)(b*NT + t) * 256 + (size_t)(tr*64) + 4*tc;

    // z broadcast + wave-uniform scale exponent (all lanes participate
    // BEFORE any divergent skip, so the wave-max sees no garbage lanes).
    const int src = (gw << 4) + tt;
    float z1 = __shfl(za.x, src);
    float z2 = __shfl(za.y, src);
    float r_  = sqrtf(z1*z1 + z2*z2);
    float th  = atan2f(z2, z1);
    if (th < 0.f) th += PI_F;
    int   idx = ((int)(th * ((float)NA / PI_F) + 0.5f)) & (NA - 1);
    float nrm = r_ * rhos[idx];
    nrm = fmaxf(nrm, __shfl_xor(nrm, 16));
    nrm = fmaxf(nrm, __shfl_xor(nrm, 32));     // uniform across the wave
    int s = 0;
    if (nrm > 1.0f) s = (int)ceilf(log2f(nrm));
    const float scl = exp2f(-(float)s);

    if (kchunk == 0 && tt == 0) {              // A[b,0] = I; M[:,0] unused
#pragma unroll
      for (int rr = 0; rr < 4; ++rr)
        *(float4*)&Aout[obase + rr*16] =
          make_float4(lt[rr*4+0], lt[rr*4+1], lt[rr*4+2], lt[rr*4+3]);
      continue;
    }
    z1 *= scl; z2 *= scl;

#pragma unroll
    for (int e = 0; e < 16; ++e) gt[e] = z1*s1t[e] + z2*s2t[e];
    st4(sb, BX, gt, trR, xD);  WSYNC();

    mmg<true>(acc, sb, BX, BX, xA, xB, trR);            // G2
    st4(sb, BY, acc, trR, xD);
#pragma unroll
    for (int e = 0; e < 16; ++e) {
      pp[e] = gt[e] + 0.5f*acc[e];
      uu[e] = C5*gt[e] + C6*acc[e];
    }
    pp[0] += trtc; pp[5] += trtc; pp[10] += trtc; pp[15] += trtc;       // + I
    uu[0] += C4*trtc; uu[5] += C4*trtc; uu[10] += C4*trtc; uu[15] += C4*trtc;
    WSYNC();

    mmg<true>(acc, sb, BY, BX, xA, xB, trR);            // G3 = G2*G
#pragma unroll
    for (int e = 0; e < 16; ++e) { pp[e] += C3*acc[e]; uu[e] += C7*acc[e]; }
    mmg<true>(acc, sb, BY, BY, xA, xB, trR);            // G4 = G2*G2
#pragma unroll
    for (int e = 0; e < 16; ++e) uu[e] += C8*acc[e];
    st4(sb, BX, acc, trR, xD);                          // BX := G4
    st4(sb, BY, uu, trR, xD);                           // BY := U
    WSYNC();

    mmg<false>(pp, sb, BX, BY, xA, xB, trR);            // E = P1 + G4*U
    int cur = BY, oth = BX;
    st4(sb, cur, pp, trR, xD); WSYNC();

    for (int q = 0; q < s; ++q) {                       // uniform trip count
      mmg<true>(acc, sb, cur, cur, xA, xB, trR);
      st4(sb, oth, acc, trR, xD); WSYNC();
      int tmp = cur; cur = oth; oth = tmp;
    }

    st4(sb, oth, lt, trR, xD); WSYNC();
    mmg<true>(acc, sb, oth, cur, xA, xB, trR);          // Lnew = L @ E
#pragma unroll
    for (int e = 0; e < 16; ++e) lt[e] = acc[e];

#pragma unroll
    for (int rr = 0; rr < 4; ++rr)
      *(float4*)&Aout[obase + rr*16] =
        make_float4(lt[rr*4+0], lt[rr*4+1], lt[rr*4+2], lt[rr*4+3]);
  }
}

// k2a: per (b, subgroup of 16 chunks): exclusive partial carries -> Binv[b,k*CH],
// subgroup total -> Binv[b, sb*256+1].
__global__ __launch_bounds__(256) void k2a(const float* __restrict__ Aout,
                                           float* __restrict__ Binv) {
  __shared__ float Cy[256], Lt[256];
  const int tid = threadIdx.x, i = tid >> 4, j = tid & 15;
  const int b = blockIdx.x >> 4, sb = blockIdx.x & 15;
  Cy[tid] = (i == j) ? 1.f : 0.f;
  float nxt = Aout[((size_t)(b*NT + (sb*16)*CH + CH - 1))*256 + tid];
  __syncthreads();
  for (int q = 0; q < 16; ++q) {
    const int k = sb*16 + q;
    Binv[((size_t)(b*NT + k*CH))*256 + tid] = Cy[tid];
    Lt[tid] = nxt;
    __syncthreads();
    if (q < 15) nxt = Aout[((size_t)(b*NT + (k+1)*CH + CH - 1))*256 + tid];
    float a2 = 0.f;
#pragma unroll
    for (int m = 0; m < 16; ++m) a2 = fmaf(Cy[i*16+m], Lt[m*16+j], a2);
    __syncthreads();
    Cy[tid] = a2;
    __syncthreads();
  }
  Binv[((size_t)(b*NT + sb*256 + 1))*256 + tid] = Cy[tid];
}

// k2b: per batch: exclusive scan over 16 subgroup totals -> supercarry at Binv[b,sb*256+2].
__global__ __launch_bounds__(256) void k2b(float* __restrict__ Binv) {
  __shared__ float Cy[256], Lt[256];
  const int tid = threadIdx.x, i = tid >> 4, j = tid & 15;
  const int b = blockIdx.x;
  Cy[tid] = (i == j) ? 1.f : 0.f;
  float nxt = Binv[((size_t)(b*NT + 1))*256 + tid];
  __syncthreads();
  for (int sb2 = 0; sb2 < 16; ++sb2) {
    Binv[((size_t)(b*NT + sb2*256 + 2))*256 + tid] = Cy[tid];
    Lt[tid] = nxt;
    __syncthreads();
    if (sb2 < 15) nxt = Binv[((size_t)(b*NT + (sb2+1)*256 + 1))*256 + tid];
    float a2 = 0.f;
#pragma unroll
    for (int m = 0; m < 16; ++m) a2 = fmaf(Cy[i*16+m], Lt[m*16+j], a2);
    __syncthreads();
    Cy[tid] = a2;
    __syncthreads();
  }
}

// k3: group-based fixup. W = Super * Partial (once per chain, kept in LDS);
// per t: A[t] = W @ L[t]  (write), Binv[t] = A[t]^T via LDS transpose.
__global__ __launch_bounds__(256, 4) void k3_apply(float* __restrict__ Aout,
                                                   float* __restrict__ Binv)
{
  __shared__ __align__(16) float lds[GPB * LGS];
  __shared__ float SupL[256];
  const int tid = threadIdx.x;
  const int g   = tid >> 4;
  const int u   = tid & 15;
  const int tr  = u >> 2;
  const int tc  = u & 3;
  const int trR = tr * ROWB;
  float* sb_ = lds + g * LGS;
  const int xA[4] = { ((0^tr)<<2), ((1^tr)<<2), ((2^tr)<<2), ((3^tr)<<2) };
  const int xB[4] = { ((tc^0)<<2), ((tc^1)<<2), ((tc^2)<<2), ((tc^3)<<2) };
  const int xD    = ((tc^tr)<<2);

  const int b   = blockIdx.x >> 4;
  const int sbq = blockIdx.x & 15;
  const int k   = sbq*16 + g;
  const int t0  = k * CH;

  SupL[tid] = Binv[((size_t)(b*NT + sbq*256 + 2))*256 + tid];
  {
    const float* srcp = &Binv[((size_t)(b*NT + k*CH))*256];
#pragma unroll
    for (int rr = 0; rr < 4; ++rr) {
      float4 v = *(const float4*)&srcp[rr*64 + 4*u];
      *(float4*)&sb_[BX + rr*ROWB + tr*16 + ((tc^rr)<<2)] = v;
    }
  }
  __syncthreads();

  float wt[16];
  {
    float* acc = wt;
#pragma unroll
    for (int e = 0; e < 16; ++e) acc[e] = 0.f;
#pragma unroll
    for (int kk = 0; kk < 4; ++kk) {
      const float* pb = sb_ + BX + kk*ROWB + xB[kk];
      float4 b0 = *(const float4*)(pb +  0);
      float4 b1 = *(const float4*)(pb + 16);
      float4 b2 = *(const float4*)(pb + 32);
      float4 b3 = *(const float4*)(pb + 48);
      float4 a0 = *(const float4*)&SupL[(4*tr+0)*16 + 4*kk];
      float4 a1 = *(const float4*)&SupL[(4*tr+1)*16 + 4*kk];
      float4 a2 = *(const float4*)&SupL[(4*tr+2)*16 + 4*kk];
      float4 a3 = *(const float4*)&SupL[(4*tr+3)*16 + 4*kk];
      MM_FMA(a0, b0, b1, b2, b3, 0)
      MM_FMA(a1, b0, b1, b2, b3, 4)
      MM_FMA(a2, b0, b1, b2, b3, 8)
      MM_FMA(a3, b0, b1, b2, b3, 12)
    }
  }
  st4(sb_, BY, wt, trR, xD);   // BY := W for the whole loop
  WSYNC();

  float acc[16];
  for (int tt = 0; tt < CH; ++tt) {
    const size_t base = ((size_t)(b*NT + t0 + tt))*256;
#pragma unroll
    for (int rr = 0; rr < 4; ++rr) {
      float4 v = *(const float4*)&Aout[base + rr*64 + 4*u];
      *(float4*)&sb_[BX + rr*ROWB + tr*16 + ((tc^rr)<<2)] = v;
    }
    WSYNC();
    mmg<true>(acc, sb_, BY, BX, xA, xB, trR);           // A = W @ L
    const size_t obase = base + (size_t)(tr*64) + 4*tc;
#pragma unroll
    for (int rr = 0; rr < 4; ++rr)
      *(float4*)&Aout[obase + rr*16] =
        make_float4(acc[rr*4+0], acc[rr*4+1], acc[rr*4+2], acc[rr*4+3]);
    st4(sb_, BX, acc, trR, xD); WSYNC();
    const float* pt = sb_ + BX + tc*ROWB + ((tr^tc)<<2);
    float4 f0 = *(const float4*)(pt +  0);
    float4 f1 = *(const float4*)(pt + 16);
    float4 f2 = *(const float4*)(pt + 32);
    float4 f3 = *(const float4*)(pt + 48);
    *(float4*)&Binv[obase +  0] = make_float4(f0.x, f1.x, f2.x, f3.x);
    *(float4*)&Binv[obase + 16] = make_float4(f0.y, f1.y, f2.y, f3.y);
    *(float4*)&Binv[obase + 32] = make_float4(f0.z, f1.z, f2.z, f3.z);
    *(float4*)&Binv[obase + 48] = make_float4(f0.w, f1.w, f2.w, f3.w);
    WSYNC();
  }
}

extern "C" void kernel_launch(void* const* d_in, const int* in_sizes, int n_in,
                              void* d_out, int out_size, void* d_ws, size_t ws_size,
                              hipStream_t stream) {
  const float* Z  = (const float*)d_in[0];
  const float* A1 = (const float*)d_in[1];
  const float* A2 = (const float*)d_in[2];
  float* ws   = (float*)d_ws;
  float* Aout = (float*)d_out;
  float* Binv = Aout + (size_t)NB * NT * 256;

  k0_spec<<<1, 128, 0, stream>>>(A1, A2, ws);
  k1_chunk<<<NB * KC / GPB, 256, 0, stream>>>(Z, A1, A2, ws, Aout);
  k2a<<<NB * 16, 256, 0, stream>>>(Aout, Binv);
  k2b<<<64, 256, 0, stream>>>(Binv);
  k3_apply<<<NB * 16, 256, 0, stream>>>(Aout, Binv);
}

// Round 6
// 614.708 us; speedup vs baseline: 1.1186x; 1.1186x over previous
//
#include <hip/hip_runtime.h>

#define NB 64
#define NT 4096
#define CH 16
#define KC (NT/CH)        // 256 chunks per batch
#define GPB 16            // chains (16-lane groups) per 256-thread block
#define ROWB 72           // floats per 4-row block: 64 data + 8 pad (8 mod 32 banks)
#define MATS (4*ROWB)     // 288 floats per matrix buffer
#define LGS (2*MATS + 8)  // 584 floats per group; 584 % 32 == 8 -> group bank shift
#define BX 0
#define BY MATS
#define NA 128            // spectral-norm table size over [0, pi)
#define PI_F 3.14159265358979f

// Wave-synchronous LDS fence (16-lane groups are sub-wave -> lockstep).
#define WSYNC() asm volatile("s_waitcnt lgkmcnt(0)" ::: "memory")

#define MM_FMA(A_, B0_, B1_, B2_, B3_, base) \
  acc[base+0] = fmaf(A_.w, B3_.x, fmaf(A_.z, B2_.x, fmaf(A_.y, B1_.x, fmaf(A_.x, B0_.x, acc[base+0])))); \
  acc[base+1] = fmaf(A_.w, B3_.y, fmaf(A_.z, B2_.y, fmaf(A_.y, B1_.y, fmaf(A_.x, B0_.y, acc[base+1])))); \
  acc[base+2] = fmaf(A_.w, B3_.z, fmaf(A_.z, B2_.z, fmaf(A_.y, B1_.z, fmaf(A_.x, B0_.z, acc[base+2])))); \
  acc[base+3] = fmaf(A_.w, B3_.w, fmaf(A_.z, B2_.w, fmaf(A_.y, B1_.w, fmaf(A_.x, B0_.w, acc[base+3]))));

// Layout: element (row,col): q=row>>2, rr=row&3, gc=col>>2 stored at
// q*ROWB + rr*16 + ((gc^q)<<2) + (col&3).
template<bool CLR>
__device__ __forceinline__ void mmg(float acc[16], const float* sb, int offA, int offB,
                                    const int xA[4], const int xB[4], int trR) {
  if (CLR) {
#pragma unroll
    for (int e = 0; e < 16; ++e) acc[e] = 0.f;
  }
#pragma unroll
  for (int kk = 0; kk < 4; ++kk) {
    const float* pa = sb + offA + trR + xA[kk];
    const float* pb = sb + offB + kk*ROWB + xB[kk];
    float4 a0 = *(const float4*)(pa +  0);
    float4 a1 = *(const float4*)(pa + 16);
    float4 a2 = *(const float4*)(pa + 32);
    float4 a3 = *(const float4*)(pa + 48);
    float4 b0 = *(const float4*)(pb +  0);
    float4 b1 = *(const float4*)(pb + 16);
    float4 b2 = *(const float4*)(pb + 32);
    float4 b3 = *(const float4*)(pb + 48);
    MM_FMA(a0, b0, b1, b2, b3, 0)
    MM_FMA(a1, b0, b1, b2, b3, 4)
    MM_FMA(a2, b0, b1, b2, b3, 8)
    MM_FMA(a3, b0, b1, b2, b3, 12)
  }
}

__device__ __forceinline__ void st4(float* sb, int offD, const float v[16], int trR, int xD) {
  float* p = sb + offD + trR + xD;
#pragma unroll
  for (int rr = 0; rr < 4; ++rr)
    *(float4*)(p + rr*16) = make_float4(v[rr*4+0], v[rr*4+1], v[rr*4+2], v[rr*4+3]);
}

// k0: spectral-norm table rho(theta)=||cos*S1+sin*S2||_2 via power iteration.
__global__ __launch_bounds__(128) void k0_spec(const float* __restrict__ A1,
                                               const float* __restrict__ A2,
                                               float* __restrict__ ws) {
  __shared__ float S1[256], S2[256];
  const int tid = threadIdx.x;
  for (int e = tid; e < 256; e += 128) {
    int i_ = e >> 4, j_ = e & 15;
    S1[e] = A1[i_*16+j_] - A1[j_*16+i_];
    S2[e] = A2[i_*16+j_] - A2[j_*16+i_];
  }
  __syncthreads();
  const float th = (float)tid * (PI_F / NA);
  const float c = cosf(th), s = sinf(th);
  float v[16];
  float n2 = 0.f;
#pragma unroll
  for (int j = 0; j < 16; ++j) { v[j] = sinf(1.7f*(float)(j+1) + th) + 0.25f; n2 += v[j]*v[j]; }
  float inv = rsqrtf(n2);
#pragma unroll
  for (int j = 0; j < 16; ++j) v[j] *= inv;
  float lam = 0.f;
  for (int it = 0; it < 14; ++it) {
    float w[16];
#pragma unroll
    for (int i = 0; i < 16; ++i) {
      float a1 = 0.f, a2 = 0.f;
#pragma unroll
      for (int j = 0; j < 16; ++j) { a1 = fmaf(S1[i*16+j], v[j], a1); a2 = fmaf(S2[i*16+j], v[j], a2); }
      w[i] = c*a1 + s*a2;
    }
    n2 = 0.f;
#pragma unroll
    for (int i = 0; i < 16; ++i) n2 += w[i]*w[i];
    lam = sqrtf(n2);
    inv = (lam > 1e-20f) ? 1.f/lam : 0.f;
#pragma unroll
    for (int i = 0; i < 16; ++i) v[i] = w[i]*inv;
  }
  ws[tid] = lam * 1.05f;
}

// k1: per-chunk local scan; streaming p/u accumulation; (256,2) -> 128-VGPR
// cap (proven no-spill in round 2); wave-uniform scaling exponent s.
__global__ __launch_bounds__(256, 2) void k1_chunk(const float* __restrict__ Z,
                                                   const float* __restrict__ A1,
                                                   const float* __restrict__ A2,
                                                   const float* __restrict__ ws,
                                                   float* __restrict__ Aout)
{
  __shared__ __align__(16) float lds[GPB * LGS];
  __shared__ float rhos[NA];
  const int tid = threadIdx.x;
  const int g   = tid >> 4;
  const int u   = tid & 15;
  const int tr  = u >> 2;
  const int tc  = u & 3;
  const int gw  = (tid & 63) >> 4;
  const int trR = tr * ROWB;

  if (tid < NA) rhos[tid] = ws[tid];
  __syncthreads();

  float* sb = lds + g * LGS;
  const int xA[4] = { ((0^tr)<<2), ((1^tr)<<2), ((2^tr)<<2), ((3^tr)<<2) };
  const int xB[4] = { ((tc^0)<<2), ((tc^1)<<2), ((tc^2)<<2), ((tc^3)<<2) };
  const int xD    = ((tc^tr)<<2);

  const int cid    = blockIdx.x * GPB + g;
  const int b      = cid >> 8;          // / KC  (KC = 256)
  const int kchunk = cid & (KC-1);
  const int t0     = kchunk * CH;

  const float trtc = (tr == tc) ? 1.f : 0.f;
  float s1t[16], s2t[16];
#pragma unroll
  for (int rr = 0; rr < 4; ++rr)
#pragma unroll
    for (int cc = 0; cc < 4; ++cc) {
      int r_ = 4*tr + rr, c_ = 4*tc + cc;
      s1t[rr*4+cc] = A1[r_*16 + c_] - A1[c_*16 + r_];
      s2t[rr*4+cc] = A2[r_*16 + c_] - A2[c_*16 + r_];
    }

  float2 za = *(const float2*)&Z[(size_t)(b*NT + t0 + u) * 2];

  float lt[16], acc[16], gt[16], pp[16], uu[16];
#pragma unroll
  for (int rr = 0; rr < 4; ++rr)
#pragma unroll
    for (int cc = 0; cc < 4; ++cc) lt[rr*4+cc] = (rr == cc) ? trtc : 0.f;

  const float C3 = 1.f/6.f,   C4 = 1.f/24.f,   C5 = 1.f/120.f,
              C6 = 1.f/720.f, C7 = 1.f/5040.f, C8 = 1.f/40320.f;

  for (int tt = 0; tt < CH; ++tt) {
    const int t = t0 + tt;
    const size_t obase = (size_t)(b*NT + t) * 256 + (size_t)(tr*64) + 4*tc;

    // z broadcast + wave-uniform scale exponent (all lanes participate
    // BEFORE any divergent skip, so the wave-max sees no garbage lanes).
    const int src = (gw << 4) + tt;
    float z1 = __shfl(za.x, src);
    float z2 = __shfl(za.y, src);
    float r_  = sqrtf(z1*z1 + z2*z2);
    float th  = atan2f(z2, z1);
    if (th < 0.f) th += PI_F;
    int   idx = ((int)(th * ((float)NA / PI_F) + 0.5f)) & (NA - 1);
    float nrm = r_ * rhos[idx];
    nrm = fmaxf(nrm, __shfl_xor(nrm, 16));
    nrm = fmaxf(nrm, __shfl_xor(nrm, 32));     // uniform across the wave
    int s = 0;
    if (nrm > 1.0f) s = (int)ceilf(log2f(nrm));
    const float scl = exp2f(-(float)s);

    if (kchunk == 0 && tt == 0) {              // A[b,0] = I; M[:,0] unused
#pragma unroll
      for (int rr = 0; rr < 4; ++rr)
        *(float4*)&Aout[obase + rr*16] =
          make_float4(lt[rr*4+0], lt[rr*4+1], lt[rr*4+2], lt[rr*4+3]);
      continue;
    }
    z1 *= scl; z2 *= scl;

#pragma unroll
    for (int e = 0; e < 16; ++e) gt[e] = z1*s1t[e] + z2*s2t[e];
    st4(sb, BX, gt, trR, xD);  WSYNC();

    mmg<true>(acc, sb, BX, BX, xA, xB, trR);            // G2
    st4(sb, BY, acc, trR, xD);
#pragma unroll
    for (int e = 0; e < 16; ++e) {
      pp[e] = gt[e] + 0.5f*acc[e];
      uu[e] = C5*gt[e] + C6*acc[e];
    }
    pp[0] += trtc; pp[5] += trtc; pp[10] += trtc; pp[15] += trtc;       // + I
    uu[0] += C4*trtc; uu[5] += C4*trtc; uu[10] += C4*trtc; uu[15] += C4*trtc;
    WSYNC();

    mmg<true>(acc, sb, BY, BX, xA, xB, trR);            // G3 = G2*G
#pragma unroll
    for (int e = 0; e < 16; ++e) { pp[e] += C3*acc[e]; uu[e] += C7*acc[e]; }
    mmg<true>(acc, sb, BY, BY, xA, xB, trR);            // G4 = G2*G2
#pragma unroll
    for (int e = 0; e < 16; ++e) uu[e] += C8*acc[e];
    st4(sb, BX, acc, trR, xD);                          // BX := G4
    st4(sb, BY, uu, trR, xD);                           // BY := U
    WSYNC();

    mmg<false>(pp, sb, BX, BY, xA, xB, trR);            // E = P1 + G4*U
    int cur = BY, oth = BX;
    st4(sb, cur, pp, trR, xD); WSYNC();

    for (int q = 0; q < s; ++q) {                       // uniform trip count
      mmg<true>(acc, sb, cur, cur, xA, xB, trR);
      st4(sb, oth, acc, trR, xD); WSYNC();
      int tmp = cur; cur = oth; oth = tmp;
    }

    st4(sb, oth, lt, trR, xD); WSYNC();
    mmg<true>(acc, sb, oth, cur, xA, xB, trR);          // Lnew = L @ E
#pragma unroll
    for (int e = 0; e < 16; ++e) lt[e] = acc[e];

#pragma unroll
    for (int rr = 0; rr < 4; ++rr)
      *(float4*)&Aout[obase + rr*16] =
        make_float4(lt[rr*4+0], lt[rr*4+1], lt[rr*4+2], lt[rr*4+3]);
  }
}

// k2a: per (b, subgroup of 16 chunks): exclusive partial carries -> Binv[b,k*CH],
// subgroup total -> Binv[b, sb*256+1].
__global__ __launch_bounds__(256) void k2a(const float* __restrict__ Aout,
                                           float* __restrict__ Binv) {
  __shared__ float Cy[256], Lt[256];
  const int tid = threadIdx.x, i = tid >> 4, j = tid & 15;
  const int b = blockIdx.x >> 4, sb = blockIdx.x & 15;
  Cy[tid] = (i == j) ? 1.f : 0.f;
  float nxt = Aout[((size_t)(b*NT + (sb*16)*CH + CH - 1))*256 + tid];
  __syncthreads();
  for (int q = 0; q < 16; ++q) {
    const int k = sb*16 + q;
    Binv[((size_t)(b*NT + k*CH))*256 + tid] = Cy[tid];
    Lt[tid] = nxt;
    __syncthreads();
    if (q < 15) nxt = Aout[((size_t)(b*NT + (k+1)*CH + CH - 1))*256 + tid];
    float a2 = 0.f;
#pragma unroll
    for (int m = 0; m < 16; ++m) a2 = fmaf(Cy[i*16+m], Lt[m*16+j], a2);
    __syncthreads();
    Cy[tid] = a2;
    __syncthreads();
  }
  Binv[((size_t)(b*NT + sb*256 + 1))*256 + tid] = Cy[tid];
}

// k2b: per batch: exclusive scan over 16 subgroup totals -> supercarry at Binv[b,sb*256+2].
__global__ __launch_bounds__(256) void k2b(float* __restrict__ Binv) {
  __shared__ float Cy[256], Lt[256];
  const int tid = threadIdx.x, i = tid >> 4, j = tid & 15;
  const int b = blockIdx.x;
  Cy[tid] = (i == j) ? 1.f : 0.f;
  float nxt = Binv[((size_t)(b*NT + 1))*256 + tid];
  __syncthreads();
  for (int sb2 = 0; sb2 < 16; ++sb2) {
    Binv[((size_t)(b*NT + sb2*256 + 2))*256 + tid] = Cy[tid];
    Lt[tid] = nxt;
    __syncthreads();
    if (sb2 < 15) nxt = Binv[((size_t)(b*NT + (sb2+1)*256 + 1))*256 + tid];
    float a2 = 0.f;
#pragma unroll
    for (int m = 0; m < 16; ++m) a2 = fmaf(Cy[i*16+m], Lt[m*16+j], a2);
    __syncthreads();
    Cy[tid] = a2;
    __syncthreads();
  }
}

// k3: group-based fixup. W = Super * Partial (once per chain, kept in LDS);
// per t: A[t] = W @ L[t]  (write), Binv[t] = A[t]^T via LDS transpose.
__global__ __launch_bounds__(256, 2) void k3_apply(float* __restrict__ Aout,
                                                   float* __restrict__ Binv)
{
  __shared__ __align__(16) float lds[GPB * LGS];
  __shared__ float SupL[256];
  const int tid = threadIdx.x;
  const int g   = tid >> 4;
  const int u   = tid & 15;
  const int tr  = u >> 2;
  const int tc  = u & 3;
  const int trR = tr * ROWB;
  float* sb_ = lds + g * LGS;
  const int xA[4] = { ((0^tr)<<2), ((1^tr)<<2), ((2^tr)<<2), ((3^tr)<<2) };
  const int xB[4] = { ((tc^0)<<2), ((tc^1)<<2), ((tc^2)<<2), ((tc^3)<<2) };
  const int xD    = ((tc^tr)<<2);

  const int b   = blockIdx.x >> 4;
  const int sbq = blockIdx.x & 15;
  const int k   = sbq*16 + g;
  const int t0  = k * CH;

  SupL[tid] = Binv[((size_t)(b*NT + sbq*256 + 2))*256 + tid];
  {
    const float* srcp = &Binv[((size_t)(b*NT + k*CH))*256];
#pragma unroll
    for (int rr = 0; rr < 4; ++rr) {
      float4 v = *(const float4*)&srcp[rr*64 + 4*u];
      *(float4*)&sb_[BX + rr*ROWB + tr*16 + ((tc^rr)<<2)] = v;
    }
  }
  __syncthreads();

  float wt[16];
  {
    float* acc = wt;
#pragma unroll
    for (int e = 0; e < 16; ++e) acc[e] = 0.f;
#pragma unroll
    for (int kk = 0; kk < 4; ++kk) {
      const float* pb = sb_ + BX + kk*ROWB + xB[kk];
      float4 b0 = *(const float4*)(pb +  0);
      float4 b1 = *(const float4*)(pb + 16);
      float4 b2 = *(const float4*)(pb + 32);
      float4 b3 = *(const float4*)(pb + 48);
      float4 a0 = *(const float4*)&SupL[(4*tr+0)*16 + 4*kk];
      float4 a1 = *(const float4*)&SupL[(4*tr+1)*16 + 4*kk];
      float4 a2 = *(const float4*)&SupL[(4*tr+2)*16 + 4*kk];
      float4 a3 = *(const float4*)&SupL[(4*tr+3)*16 + 4*kk];
      MM_FMA(a0, b0, b1, b2, b3, 0)
      MM_FMA(a1, b0, b1, b2, b3, 4)
      MM_FMA(a2, b0, b1, b2, b3, 8)
      MM_FMA(a3, b0, b1, b2, b3, 12)
    }
  }
  st4(sb_, BY, wt, trR, xD);   // BY := W for the whole loop
  WSYNC();

  float acc[16];
  for (int tt = 0; tt < CH; ++tt) {
    const size_t base = ((size_t)(b*NT + t0 + tt))*256;
#pragma unroll
    for (int rr = 0; rr < 4; ++rr) {
      float4 v = *(const float4*)&Aout[base + rr*64 + 4*u];
      *(float4*)&sb_[BX + rr*ROWB + tr*16 + ((tc^rr)<<2)] = v;
    }
    WSYNC();
    mmg<true>(acc, sb_, BY, BX, xA, xB, trR);           // A = W @ L
    const size_t obase = base + (size_t)(tr*64) + 4*tc;
#pragma unroll
    for (int rr = 0; rr < 4; ++rr)
      *(float4*)&Aout[obase + rr*16] =
        make_float4(acc[rr*4+0], acc[rr*4+1], acc[rr*4+2], acc[rr*4+3]);
    st4(sb_, BX, acc, trR, xD); WSYNC();
    const float* pt = sb_ + BX + tc*ROWB + ((tr^tc)<<2);
    float4 f0 = *(const float4*)(pt +  0);
    float4 f1 = *(const float4*)(pt + 16);
    float4 f2 = *(const float4*)(pt + 32);
    float4 f3 = *(const float4*)(pt + 48);
    *(float4*)&Binv[obase +  0] = make_float4(f0.x, f1.x, f2.x, f3.x);
    *(float4*)&Binv[obase + 16] = make_float4(f0.y, f1.y, f2.y, f3.y);
    *(float4*)&Binv[obase + 32] = make_float4(f0.z, f1.z, f2.z, f3.z);
    *(float4*)&Binv[obase + 48] = make_float4(f0.w, f1.w, f2.w, f3.w);
    WSYNC();
  }
}

extern "C" void kernel_launch(void* const* d_in, const int* in_sizes, int n_in,
                              void* d_out, int out_size, void* d_ws, size_t ws_size,
                              hipStream_t stream) {
  const float* Z  = (const float*)d_in[0];
  const float* A1 = (const float*)d_in[1];
  const float* A2 = (const float*)d_in[2];
  float* ws   = (float*)d_ws;
  float* Aout = (float*)d_out;
  float* Binv = Aout + (size_t)NB * NT * 256;

  k0_spec<<<1, 128, 0, stream>>>(A1, A2, ws);
  k1_chunk<<<NB * KC / GPB, 256, 0, stream>>>(Z, A1, A2, ws, Aout);
  k2a<<<NB * 16, 256, 0, stream>>>(Aout, Binv);
  k2b<<<64, 256, 0, stream>>>(Binv);
  k3_apply<<<NB * 16, 256, 0, stream>>>(Aout, Binv);
}

// Round 7
// 538.817 us; speedup vs baseline: 1.2761x; 1.1408x over previous
//
#include <hip/hip_runtime.h>

#define NB 64
#define NT 4096
#define CH 16
#define KC (NT/CH)        // 256 chunks per batch
#define GPB 16            // chains (16-lane groups) per 256-thread block
#define NA 128            // spectral-norm table size over [0, pi)
#define NM 14             // hoisted G-power basis matrices
#define PI_F 3.14159265358979f

#define C3c (1.f/6.f)
#define C4c (1.f/24.f)
#define C5c (1.f/120.f)
#define C6c (1.f/720.f)
#define C7c (1.f/5040.f)
#define C8c (1.f/40320.f)

// ---------------- register-resident 16x16 matmul ----------------
// Lane grid per 16-lane group: lane u = 4*tr+tc holds tile X[4tr+rr][4tc+cc]
// at x[rr*4+cc]. For C += A*B:
//   A-slice (tr,K): owner is quad-mate slot K -> DPP quad_perm[K,K,K,K].
//   B-slice (K,tc): owner lane (K,tc) -> ds_swizzle BitMode
//     src_lane = (lane & 0x13) | (K<<2)   (keeps bit4=group-in-half and tc).
template<int K>
__device__ __forceinline__ void mm_step(float acc[16], const float a[16], const float b[16]) {
  float bb[16];
#pragma unroll
  for (int e = 0; e < 16; ++e)
    bb[e] = __int_as_float(__builtin_amdgcn_ds_swizzle(__float_as_int(b[e]), (K << 7) | 0x13));
#pragma unroll
  for (int rr = 0; rr < 4; ++rr) {
    const float a0 = __int_as_float(__builtin_amdgcn_mov_dpp(__float_as_int(a[rr*4+0]), K*0x55, 0xF, 0xF, true));
    const float a1 = __int_as_float(__builtin_amdgcn_mov_dpp(__float_as_int(a[rr*4+1]), K*0x55, 0xF, 0xF, true));
    const float a2 = __int_as_float(__builtin_amdgcn_mov_dpp(__float_as_int(a[rr*4+2]), K*0x55, 0xF, 0xF, true));
    const float a3 = __int_as_float(__builtin_amdgcn_mov_dpp(__float_as_int(a[rr*4+3]), K*0x55, 0xF, 0xF, true));
#pragma unroll
    for (int cc = 0; cc < 4; ++cc)
      acc[rr*4+cc] = fmaf(a3, bb[12+cc], fmaf(a2, bb[8+cc], fmaf(a1, bb[4+cc], fmaf(a0, bb[cc], acc[rr*4+cc]))));
  }
}
__device__ __forceinline__ void mmreg(float acc[16], const float a[16], const float b[16]) {
  mm_step<0>(acc, a, b); mm_step<1>(acc, a, b);
  mm_step<2>(acc, a, b); mm_step<3>(acc, a, b);
}

// ---------------- k0: rho table + hoisted G-power basis ----------------
// ws[0..127]  : rho(theta) spectral-norm table
// ws[128 + m*256 + e], m=0..13:
//   M0=S1 M1=S2 | M2=S1S1 M3=S1S2+S2S1 M4=S2S2 | M5..M8 = cubic word-sums by
//   #S2 | M9..M13 = quartic word-sums by #S2.  Then G^n(z1,z2) = sum over the
//   degree-n bucket of z1^(n-j) z2^j * M.
__global__ __launch_bounds__(256) void k0_prep(const float* __restrict__ A1,
                                               const float* __restrict__ A2,
                                               float* __restrict__ ws) {
  __shared__ float S[2][256], W2[4][256], W3[8][256], W4[16][256];
  const int tid = threadIdx.x;
  {
    int i_ = tid >> 4, j_ = tid & 15;
    S[0][tid] = A1[i_*16+j_] - A1[j_*16+i_];
    S[1][tid] = A2[i_*16+j_] - A2[j_*16+i_];
  }
  __syncthreads();
  const int i = tid >> 4, j = tid & 15;
#pragma unroll
  for (int p = 0; p < 4; ++p) {
    const float* a = S[p>>1]; const float* bm = S[p&1];
    float acc = 0.f;
    for (int k = 0; k < 16; ++k) acc = fmaf(a[i*16+k], bm[k*16+j], acc);
    W2[p][tid] = acc;
  }
  __syncthreads();
#pragma unroll
  for (int p = 0; p < 8; ++p) {
    const float* a = S[p>>2]; const float* bm = W2[p&3];
    float acc = 0.f;
    for (int k = 0; k < 16; ++k) acc = fmaf(a[i*16+k], bm[k*16+j], acc);
    W3[p][tid] = acc;
  }
  __syncthreads();
#pragma unroll
  for (int p = 0; p < 16; ++p) {
    const float* a = S[p>>3]; const float* bm = W3[p&7];
    float acc = 0.f;
    for (int k = 0; k < 16; ++k) acc = fmaf(a[i*16+k], bm[k*16+j], acc);
    W4[p][tid] = acc;
  }
  __syncthreads();
  float* M = ws + NA;
  M[ 0*256+tid] = S[0][tid];
  M[ 1*256+tid] = S[1][tid];
  M[ 2*256+tid] = W2[0][tid];
  M[ 3*256+tid] = W2[1][tid] + W2[2][tid];
  M[ 4*256+tid] = W2[3][tid];
  M[ 5*256+tid] = W3[0][tid];
  M[ 6*256+tid] = W3[1][tid] + W3[2][tid] + W3[4][tid];
  M[ 7*256+tid] = W3[3][tid] + W3[5][tid] + W3[6][tid];
  M[ 8*256+tid] = W3[7][tid];
  M[ 9*256+tid] = W4[0][tid];
  M[10*256+tid] = W4[1][tid] + W4[2][tid] + W4[4][tid] + W4[8][tid];
  M[11*256+tid] = W4[3][tid] + W4[5][tid] + W4[6][tid] + W4[9][tid] + W4[10][tid] + W4[12][tid];
  M[12*256+tid] = W4[7][tid] + W4[11][tid] + W4[13][tid] + W4[14][tid];
  M[13*256+tid] = W4[15][tid];
  // rho table via power iteration on cos*S1 + sin*S2
  if (tid < NA) {
    const float th = (float)tid * (PI_F / NA);
    const float c = cosf(th), s = sinf(th);
    float v[16];
    float n2 = 0.f;
#pragma unroll
    for (int jj = 0; jj < 16; ++jj) { v[jj] = sinf(1.7f*(float)(jj+1) + th) + 0.25f; n2 += v[jj]*v[jj]; }
    float inv = rsqrtf(n2);
#pragma unroll
    for (int jj = 0; jj < 16; ++jj) v[jj] *= inv;
    float lam = 0.f;
    for (int it = 0; it < 14; ++it) {
      float w[16];
#pragma unroll
      for (int ii = 0; ii < 16; ++ii) {
        float a1 = 0.f, a2 = 0.f;
#pragma unroll
        for (int jj = 0; jj < 16; ++jj) { a1 = fmaf(S[0][ii*16+jj], v[jj], a1); a2 = fmaf(S[1][ii*16+jj], v[jj], a2); }
        w[ii] = c*a1 + s*a2;
      }
      n2 = 0.f;
#pragma unroll
      for (int ii = 0; ii < 16; ++ii) n2 += w[ii]*w[ii];
      lam = sqrtf(n2);
      inv = (lam > 1e-20f) ? 1.f/lam : 0.f;
#pragma unroll
      for (int ii = 0; ii < 16; ++ii) v[ii] = w[ii]*inv;
    }
    ws[tid] = lam * 1.05f;
  }
}

// ---------------- k1: per-chunk scan, fully register-resident mms ----------------
__global__ __launch_bounds__(256, 2) void k1_chunk(const float* __restrict__ Z,
                                                   const float* __restrict__ wsrc,
                                                   float* __restrict__ Aout)
{
  __shared__ float Qs[NM*256];
  __shared__ float rhos[NA];
  const int tid = threadIdx.x;
  for (int e = tid; e < NM*256; e += 256) Qs[e] = wsrc[NA + e];
  if (tid < NA) rhos[tid] = wsrc[tid];
  __syncthreads();

  const int g  = tid >> 4;
  const int u  = tid & 15;
  const int tr = u >> 2;
  const int tc = u & 3;
  const int gw = (tid & 63) >> 4;
  const int qbase = (4*tr)*16 + 4*tc;   // + m*256 + rr*16 (imm offsets)

  const int cid    = blockIdx.x * GPB + g;
  const int b      = cid >> 8;          // / KC (KC=256)
  const int kchunk = cid & (KC-1);
  const int t0     = kchunk * CH;

  const float trtc = (tr == tc) ? 1.f : 0.f;
  float2 za = *(const float2*)&Z[(size_t)(b*NT + t0 + u) * 2];

  float lt[16];
#pragma unroll
  for (int rr = 0; rr < 4; ++rr)
#pragma unroll
    for (int cc = 0; cc < 4; ++cc) lt[rr*4+cc] = (rr == cc) ? trtc : 0.f;

  for (int tt = 0; tt < CH; ++tt) {
    const size_t obase = (size_t)(b*NT + t0 + tt) * 256 + (size_t)(tr*64) + 4*tc;

    const int src = (gw << 4) + tt;
    float z1 = __shfl(za.x, src);
    float z2 = __shfl(za.y, src);
    float r_ = sqrtf(z1*z1 + z2*z2);
    float th = atan2f(z2, z1);
    if (th < 0.f) th += PI_F;
    int idx = ((int)(th * ((float)NA / PI_F) + 0.5f)) & (NA - 1);
    float nrm = r_ * rhos[idx];
    nrm = fmaxf(nrm, __shfl_xor(nrm, 16));
    nrm = fmaxf(nrm, __shfl_xor(nrm, 32));     // wave-uniform
    int s = 0;
    if (nrm > 1.0f) s = (int)ceilf(log2f(nrm));
    const float scl = exp2f(-(float)s);

    if (kchunk == 0 && tt == 0) {              // A[b,0]=I; M[:,0] unused
#pragma unroll
      for (int rr = 0; rr < 4; ++rr)
        *(float4*)&Aout[obase + rr*16] =
          make_float4(lt[rr*4+0], lt[rr*4+1], lt[rr*4+2], lt[rr*4+3]);
      continue;
    }

    const float x = z1*scl, y = z2*scl;
    const float x2 = x*x, xy = x*y, y2 = y*y;
    const float x3 = x2*x, x2y = x2*y, xy2 = x*y2, y3 = y2*y;
    const float zc[NM] = { x, y, x2, xy, y2, x3, x2y, xy2, y3,
                           x2*x2, x3*y, x2*y2, x*y3, y2*y2 };
    const float WP[NM] = { 1.f,1.f, .5f,.5f,.5f, C3c,C3c,C3c,C3c, 0.f,0.f,0.f,0.f,0.f };
    const float WU[NM] = { C5c,C5c, C6c,C6c,C6c, C7c,C7c,C7c,C7c, C8c,C8c,C8c,C8c,C8c };

    float pp[16], uu[16], g4[16];
#pragma unroll
    for (int rr = 0; rr < 4; ++rr)
#pragma unroll
      for (int cc = 0; cc < 4; ++cc) {
        pp[rr*4+cc] = (rr == cc) ? trtc : 0.f;          // I
        uu[rr*4+cc] = (rr == cc) ? trtc * C4c : 0.f;    // I/24
        g4[rr*4+cc] = 0.f;
      }
    // P1 = I + G + G2/2 + G3/6 ; U = I/24 + G/120 + G2/720 + G3/5040 + G4/40320
#pragma unroll
    for (int m = 0; m < NM; ++m) {
      const float am = zc[m] * WP[m];
      const float bm = zc[m] * WU[m];
#pragma unroll
      for (int rr = 0; rr < 4; ++rr) {
        float4 v = *(const float4*)&Qs[m*256 + rr*16 + qbase];
        if (m < 9) {
          pp[rr*4+0] = fmaf(am, v.x, pp[rr*4+0]);
          pp[rr*4+1] = fmaf(am, v.y, pp[rr*4+1]);
          pp[rr*4+2] = fmaf(am, v.z, pp[rr*4+2]);
          pp[rr*4+3] = fmaf(am, v.w, pp[rr*4+3]);
        } else {
          g4[rr*4+0] = fmaf(zc[m], v.x, g4[rr*4+0]);
          g4[rr*4+1] = fmaf(zc[m], v.y, g4[rr*4+1]);
          g4[rr*4+2] = fmaf(zc[m], v.z, g4[rr*4+2]);
          g4[rr*4+3] = fmaf(zc[m], v.w, g4[rr*4+3]);
        }
        uu[rr*4+0] = fmaf(bm, v.x, uu[rr*4+0]);
        uu[rr*4+1] = fmaf(bm, v.y, uu[rr*4+1]);
        uu[rr*4+2] = fmaf(bm, v.z, uu[rr*4+2]);
        uu[rr*4+3] = fmaf(bm, v.w, uu[rr*4+3]);
      }
    }

    mmreg(pp, g4, uu);                         // E = P1 + G4*U  (into pp)

    for (int q = 0; q < s; ++q) {              // wave-uniform squarings
      float acc[16];
#pragma unroll
      for (int e = 0; e < 16; ++e) acc[e] = 0.f;
      mmreg(acc, pp, pp);
#pragma unroll
      for (int e = 0; e < 16; ++e) pp[e] = acc[e];
    }
    {
      float acc[16];
#pragma unroll
      for (int e = 0; e < 16; ++e) acc[e] = 0.f;
      mmreg(acc, lt, pp);                      // Lnew = L @ E
#pragma unroll
      for (int e = 0; e < 16; ++e) lt[e] = acc[e];
    }
#pragma unroll
    for (int rr = 0; rr < 4; ++rr)
      *(float4*)&Aout[obase + rr*16] =
        make_float4(lt[rr*4+0], lt[rr*4+1], lt[rr*4+2], lt[rr*4+3]);
  }
}

// ---------------- carry tree + fixup (unchanged from round 6) ----------------
#define ROWB 72
#define MATS (4*ROWB)
#define LGS (2*MATS + 8)
#define BX 0
#define BY MATS
#define WSYNC() asm volatile("s_waitcnt lgkmcnt(0)" ::: "memory")

#define MM_FMA(A_, B0_, B1_, B2_, B3_, base) \
  acc[base+0] = fmaf(A_.w, B3_.x, fmaf(A_.z, B2_.x, fmaf(A_.y, B1_.x, fmaf(A_.x, B0_.x, acc[base+0])))); \
  acc[base+1] = fmaf(A_.w, B3_.y, fmaf(A_.z, B2_.y, fmaf(A_.y, B1_.y, fmaf(A_.x, B0_.y, acc[base+1])))); \
  acc[base+2] = fmaf(A_.w, B3_.z, fmaf(A_.z, B2_.z, fmaf(A_.y, B1_.z, fmaf(A_.x, B0_.z, acc[base+2])))); \
  acc[base+3] = fmaf(A_.w, B3_.w, fmaf(A_.z, B2_.w, fmaf(A_.y, B1_.w, fmaf(A_.x, B0_.w, acc[base+3]))));

template<bool CLR>
__device__ __forceinline__ void mmg(float acc[16], const float* sb, int offA, int offB,
                                    const int xA[4], const int xB[4], int trR) {
  if (CLR) {
#pragma unroll
    for (int e = 0; e < 16; ++e) acc[e] = 0.f;
  }
#pragma unroll
  for (int kk = 0; kk < 4; ++kk) {
    const float* pa = sb + offA + trR + xA[kk];
    const float* pb = sb + offB + kk*ROWB + xB[kk];
    float4 a0 = *(const float4*)(pa +  0);
    float4 a1 = *(const float4*)(pa + 16);
    float4 a2 = *(const float4*)(pa + 32);
    float4 a3 = *(const float4*)(pa + 48);
    float4 b0 = *(const float4*)(pb +  0);
    float4 b1 = *(const float4*)(pb + 16);
    float4 b2 = *(const float4*)(pb + 32);
    float4 b3 = *(const float4*)(pb + 48);
    MM_FMA(a0, b0, b1, b2, b3, 0)
    MM_FMA(a1, b0, b1, b2, b3, 4)
    MM_FMA(a2, b0, b1, b2, b3, 8)
    MM_FMA(a3, b0, b1, b2, b3, 12)
  }
}

__device__ __forceinline__ void st4(float* sb, int offD, const float v[16], int trR, int xD) {
  float* p = sb + offD + trR + xD;
#pragma unroll
  for (int rr = 0; rr < 4; ++rr)
    *(float4*)(p + rr*16) = make_float4(v[rr*4+0], v[rr*4+1], v[rr*4+2], v[rr*4+3]);
}

__global__ __launch_bounds__(256) void k2a(const float* __restrict__ Aout,
                                           float* __restrict__ Binv) {
  __shared__ float Cy[256], Lt[256];
  const int tid = threadIdx.x, i = tid >> 4, j = tid & 15;
  const int b = blockIdx.x >> 4, sb = blockIdx.x & 15;
  Cy[tid] = (i == j) ? 1.f : 0.f;
  float nxt = Aout[((size_t)(b*NT + (sb*16)*CH + CH - 1))*256 + tid];
  __syncthreads();
  for (int q = 0; q < 16; ++q) {
    const int k = sb*16 + q;
    Binv[((size_t)(b*NT + k*CH))*256 + tid] = Cy[tid];
    Lt[tid] = nxt;
    __syncthreads();
    if (q < 15) nxt = Aout[((size_t)(b*NT + (k+1)*CH + CH - 1))*256 + tid];
    float a2 = 0.f;
#pragma unroll
    for (int m = 0; m < 16; ++m) a2 = fmaf(Cy[i*16+m], Lt[m*16+j], a2);
    __syncthreads();
    Cy[tid] = a2;
    __syncthreads();
  }
  Binv[((size_t)(b*NT + sb*256 + 1))*256 + tid] = Cy[tid];
}

__global__ __launch_bounds__(256) void k2b(float* __restrict__ Binv) {
  __shared__ float Cy[256], Lt[256];
  const int tid = threadIdx.x, i = tid >> 4, j = tid & 15;
  const int b = blockIdx.x;
  Cy[tid] = (i == j) ? 1.f : 0.f;
  float nxt = Binv[((size_t)(b*NT + 1))*256 + tid];
  __syncthreads();
  for (int sb2 = 0; sb2 < 16; ++sb2) {
    Binv[((size_t)(b*NT + sb2*256 + 2))*256 + tid] = Cy[tid];
    Lt[tid] = nxt;
    __syncthreads();
    if (sb2 < 15) nxt = Binv[((size_t)(b*NT + (sb2+1)*256 + 1))*256 + tid];
    float a2 = 0.f;
#pragma unroll
    for (int m = 0; m < 16; ++m) a2 = fmaf(Cy[i*16+m], Lt[m*16+j], a2);
    __syncthreads();
    Cy[tid] = a2;
    __syncthreads();
  }
}

__global__ __launch_bounds__(256, 2) void k3_apply(float* __restrict__ Aout,
                                                   float* __restrict__ Binv)
{
  __shared__ __align__(16) float lds[GPB * LGS];
  __shared__ float SupL[256];
  const int tid = threadIdx.x;
  const int g   = tid >> 4;
  const int u   = tid & 15;
  const int tr  = u >> 2;
  const int tc  = u & 3;
  const int trR = tr * ROWB;
  float* sb_ = lds + g * LGS;
  const int xA[4] = { ((0^tr)<<2), ((1^tr)<<2), ((2^tr)<<2), ((3^tr)<<2) };
  const int xB[4] = { ((tc^0)<<2), ((tc^1)<<2), ((tc^2)<<2), ((tc^3)<<2) };
  const int xD    = ((tc^tr)<<2);

  const int b   = blockIdx.x >> 4;
  const int sbq = blockIdx.x & 15;
  const int k   = sbq*16 + g;
  const int t0  = k * CH;

  SupL[tid] = Binv[((size_t)(b*NT + sbq*256 + 2))*256 + tid];
  {
    const float* srcp = &Binv[((size_t)(b*NT + k*CH))*256];
#pragma unroll
    for (int rr = 0; rr < 4; ++rr) {
      float4 v = *(const float4*)&srcp[rr*64 + 4*u];
      *(float4*)&sb_[BX + rr*ROWB + tr*16 + ((tc^rr)<<2)] = v;
    }
  }
  __syncthreads();

  float wt[16];
  {
    float* acc = wt;
#pragma unroll
    for (int e = 0; e < 16; ++e) acc[e] = 0.f;
#pragma unroll
    for (int kk = 0; kk < 4; ++kk) {
      const float* pb = sb_ + BX + kk*ROWB + xB[kk];
      float4 b0 = *(const float4*)(pb +  0);
      float4 b1 = *(const float4*)(pb + 16);
      float4 b2 = *(const float4*)(pb + 32);
      float4 b3 = *(const float4*)(pb + 48);
      float4 a0 = *(const float4*)&SupL[(4*tr+0)*16 + 4*kk];
      float4 a1 = *(const float4*)&SupL[(4*tr+1)*16 + 4*kk];
      float4 a2 = *(const float4*)&SupL[(4*tr+2)*16 + 4*kk];
      float4 a3 = *(const float4*)&SupL[(4*tr+3)*16 + 4*kk];
      MM_FMA(a0, b0, b1, b2, b3, 0)
      MM_FMA(a1, b0, b1, b2, b3, 4)
      MM_FMA(a2, b0, b1, b2, b3, 8)
      MM_FMA(a3, b0, b1, b2, b3, 12)
    }
  }
  st4(sb_, BY, wt, trR, xD);
  WSYNC();

  float acc[16];
  for (int tt = 0; tt < CH; ++tt) {
    const size_t base = ((size_t)(b*NT + t0 + tt))*256;
#pragma unroll
    for (int rr = 0; rr < 4; ++rr) {
      float4 v = *(const float4*)&Aout[base + rr*64 + 4*u];
      *(float4*)&sb_[BX + rr*ROWB + tr*16 + ((tc^rr)<<2)] = v;
    }
    WSYNC();
    mmg<true>(acc, sb_, BY, BX, xA, xB, trR);
    const size_t obase = base + (size_t)(tr*64) + 4*tc;
#pragma unroll
    for (int rr = 0; rr < 4; ++rr)
      *(float4*)&Aout[obase + rr*16] =
        make_float4(acc[rr*4+0], acc[rr*4+1], acc[rr*4+2], acc[rr*4+3]);
    st4(sb_, BX, acc, trR, xD); WSYNC();
    const float* pt = sb_ + BX + tc*ROWB + ((tr^tc)<<2);
    float4 f0 = *(const float4*)(pt +  0);
    float4 f1 = *(const float4*)(pt + 16);
    float4 f2 = *(const float4*)(pt + 32);
    float4 f3 = *(const float4*)(pt + 48);
    *(float4*)&Binv[obase +  0] = make_float4(f0.x, f1.x, f2.x, f3.x);
    *(float4*)&Binv[obase + 16] = make_float4(f0.y, f1.y, f2.y, f3.y);
    *(float4*)&Binv[obase + 32] = make_float4(f0.z, f1.z, f2.z, f3.z);
    *(float4*)&Binv[obase + 48] = make_float4(f0.w, f1.w, f2.w, f3.w);
    WSYNC();
  }
}

extern "C" void kernel_launch(void* const* d_in, const int* in_sizes, int n_in,
                              void* d_out, int out_size, void* d_ws, size_t ws_size,
                              hipStream_t stream) {
  const float* Z  = (const float*)d_in[0];
  const float* A1 = (const float*)d_in[1];
  const float* A2 = (const float*)d_in[2];
  float* ws   = (float*)d_ws;
  float* Aout = (float*)d_out;
  float* Binv = Aout + (size_t)NB * NT * 256;

  k0_prep<<<1, 256, 0, stream>>>(A1, A2, ws);
  k1_chunk<<<NB * KC / GPB, 256, 0, stream>>>(Z, ws, Aout);
  k2a<<<NB * 16, 256, 0, stream>>>(Aout, Binv);
  k2b<<<NB, 256, 0, stream>>>(Binv);
  k3_apply<<<NB * 16, 256, 0, stream>>>(Aout, Binv);
}